// Round 1
// baseline (459.298 us; speedup 1.0000x reference)
//
#include <hip/hip_runtime.h>
#include <float.h>
#include <math.h>

#define THREADS 256

// ---------------------------------------------------------------------------
// Deterministic block reductions (256 threads = 4 waves of 64).
// shfl tree within wave, then fixed-order combine of the 4 wave results.
// ---------------------------------------------------------------------------
__device__ __forceinline__ void block_argmax(float& v, int& idx, float* wv, int* wi, int tid) {
    #pragma unroll
    for (int m = 32; m >= 1; m >>= 1) {
        float ov = __shfl_xor(v, m, 64);
        int   oi = __shfl_xor(idx, m, 64);
        if (ov > v || (ov == v && oi < idx)) { v = ov; idx = oi; }
    }
    if ((tid & 63) == 0) { wv[tid >> 6] = v; wi[tid >> 6] = idx; }
    __syncthreads();
    if (tid == 0) {
        float bv = wv[0]; int bi = wi[0];
        #pragma unroll
        for (int w = 1; w < 4; ++w) {
            float cv = wv[w]; int ci = wi[w];
            if (cv > bv || (cv == bv && ci < bi)) { bv = cv; bi = ci; }
        }
        wv[0] = bv; wi[0] = bi;
    }
    __syncthreads();
    v = wv[0]; idx = wi[0];
    __syncthreads();   // protect wv/wi reuse by caller
}

__device__ __forceinline__ float block_sum(float v, float* wv, int tid) {
    #pragma unroll
    for (int m = 32; m >= 1; m >>= 1) v += __shfl_xor(v, m, 64);
    if ((tid & 63) == 0) wv[tid >> 6] = v;
    __syncthreads();
    if (tid == 0) wv[0] = wv[0] + wv[1] + wv[2] + wv[3];
    __syncthreads();
    float r = wv[0];
    __syncthreads();
    return r;
}

// ---------------------------------------------------------------------------
// Kernel A: W[HH][S] -> Wt[S][HH]  (tiled 32x32 transpose)
// ---------------------------------------------------------------------------
__global__ __launch_bounds__(256) void transposeW(const float* __restrict__ W,
                                                  float* __restrict__ Wt,
                                                  int S, int HH) {
    __shared__ float tile[32][33];
    int x  = blockIdx.x * 32 + threadIdx.x;  // s (read)
    int y0 = blockIdx.y * 32;                // h base
    #pragma unroll
    for (int i = threadIdx.y; i < 32; i += 8) {
        int h = y0 + i;
        if (x < S && h < HH) tile[i][threadIdx.x] = W[(size_t)h * S + x];
    }
    __syncthreads();
    #pragma unroll
    for (int i = threadIdx.y; i < 32; i += 8) {
        int s = blockIdx.x * 32 + i;
        int h = y0 + threadIdx.x;
        if (s < S && h < HH) Wt[(size_t)s * HH + h] = tile[threadIdx.x][i];
    }
}

// ---------------------------------------------------------------------------
// Kernel B: per row — copy predictions_globals to out, exact top-8 indices.
// Per-thread sorted top-8 in registers (static indexing only), then 8 rounds
// of deterministic block argmax (tie-break: lowest index, matching lax.top_k
// stable-sort semantics).
// ---------------------------------------------------------------------------
__global__ __launch_bounds__(THREADS) void copy_topk(const float* __restrict__ pg,
                                                     float* __restrict__ outg,
                                                     int* __restrict__ topk,
                                                     int V) {
    const int row = blockIdx.x, tid = threadIdx.x;
    const float4* in4  = (const float4*)(pg   + (size_t)row * V);
    float4*       out4 = (float4*)(outg + (size_t)row * V);
    const int nv = V >> 2;

    float tv[8]; int ti[8];
    #pragma unroll
    for (int p = 0; p < 8; ++p) { tv[p] = -FLT_MAX; ti[p] = 0x7fffffff; }

    for (int i = tid; i < nv; i += THREADS) {
        float4 val = in4[i];
        out4[i] = val;
        const int base = i << 2;
        #pragma unroll
        for (int c = 0; c < 4; ++c) {
            float v = (c == 0) ? val.x : (c == 1) ? val.y : (c == 2) ? val.z : val.w;
            if (v > tv[7]) {              // strict >: equal keeps earlier (lower) index
                tv[7] = v; ti[7] = base + c;
                #pragma unroll
                for (int p = 7; p > 0; --p) {
                    if (tv[p] > tv[p - 1]) {
                        float tf = tv[p]; tv[p] = tv[p - 1]; tv[p - 1] = tf;
                        int   tt = ti[p]; ti[p] = ti[p - 1]; ti[p - 1] = tt;
                    }
                }
            }
        }
    }

    __shared__ float wv[4];
    __shared__ int   wi[4];
    for (int r = 0; r < 8; ++r) {
        float v = tv[0]; int idx = ti[0];
        block_argmax(v, idx, wv, wi, tid);
        if (ti[0] == idx) {               // unique owner pops its head
            #pragma unroll
            for (int p = 0; p < 7; ++p) { tv[p] = tv[p + 1]; ti[p] = ti[p + 1]; }
            tv[7] = -FLT_MAX; ti[7] = 0x7fffffff;
        }
        if (tid == 0) topk[row * 8 + r] = idx;
    }
}

// ---------------------------------------------------------------------------
// Kernel C: per row — neighbor gather, dedup, masked logits, softmax,
// delta subtraction at argmax, write log-probs (log(EPS) off-mask).
// ---------------------------------------------------------------------------
__global__ __launch_bounds__(THREADS) void senses_kernel(const float* __restrict__ hidden,
                                                         const float* __restrict__ Wt,
                                                         const float* __restrict__ bias,
                                                         const int* __restrict__ graph,
                                                         const int* __restrict__ topk,
                                                         float* __restrict__ outS,
                                                         int S, int HH, int NBR) {
    const int row = blockIdx.x, tid = threadIdx.x;
    __shared__ float sh_h[THREADS];          // hidden row (HH == 256)
    __shared__ int   cand[THREADS];
    __shared__ int   kk[8];
    __shared__ float wv[4];
    __shared__ int   wi[4];
    __shared__ int   s_cnt;

    sh_h[tid] = hidden[(size_t)row * HH + tid];
    if (tid < 8) kk[tid] = topk[row * 8 + tid];
    if (tid == 0) s_cnt = 0;
    __syncthreads();

    // gather candidate neighbours: 8 top-K rows x 32 neighbours, coalesced
    const int j = tid >> 5, c = tid & 31;
    const int g = graph[(size_t)(kk[j] + S) * NBR + c] - 1;
    int my = (g >= 0 && g < S) ? g : -1;
    cand[tid] = my;
    __syncthreads();

    // deterministic dedup: owner = lowest tid holding this sense
    bool owner = (my >= 0);
    if (owner) {
        for (int t = 0; t < tid; ++t) {
            if (cand[t] == my) { owner = false; break; }
        }
    }
    if (owner) atomicAdd(&s_cnt, 1);        // order-independent count

    // fill output row with log(EPS) while dedup/count settles
    const float LOGEPS = -18.420680743952367f;   // logf(1e-8f)
    float4* o4 = (float4*)(outS + (size_t)row * S);
    const float4 f4 = make_float4(LOGEPS, LOGEPS, LOGEPS, LOGEPS);
    const int nv = S >> 2;
    for (int i = tid; i < nv; i += THREADS) o4[i] = f4;
    __syncthreads();   // count final + fill visible block-wide

    int nsel = s_cnt;
    if (nsel == 0) {                         // zero-neighbour fallback: sense 0
        if (tid == 0) { owner = true; my = 0; }
        nsel = 1;
    }

    // masked logits: dot(hidden_row, Wt[sense]) + b[sense]
    float logit = -FLT_MAX;
    if (owner) {
        float acc = 0.f;
        const float4* wp = (const float4*)(Wt + (size_t)my * HH);
        const float4* h4 = (const float4*)sh_h;
        #pragma unroll 8
        for (int i = 0; i < (256 >> 2); ++i) {
            float4 w = wp[i];
            float4 h = h4[i];
            acc += w.x * h.x + w.y * h.y + w.z * h.z + w.w * h.w;
        }
        logit = acc + bias[my];
    }

    // softmax over owners (argmax of p == argmax of logit; tie -> lowest sense)
    float mv = logit;
    int   ai = owner ? my : 0x7fffffff;
    block_argmax(mv, ai, wv, wi, tid);

    const float e = owner ? expf(logit - mv) : 0.f;
    const float sum = block_sum(e, wv, tid);

    if (owner) {
        float p = e / sum;
        if (my == ai) p -= 1e-8f * (float)(S - nsel);   // subtract mass at argmax
        outS[(size_t)row * S + my] = logf(p);
    }
}

// ---------------------------------------------------------------------------
extern "C" void kernel_launch(void* const* d_in, const int* in_sizes, int n_in,
                              void* d_out, int out_size, void* d_ws, size_t ws_size,
                              hipStream_t stream) {
    const float* hidden = (const float*)d_in[0];
    const float* pg     = (const float*)d_in[1];
    const float* W      = (const float*)d_in[2];
    const float* bias   = (const float*)d_in[3];
    const int*   graph  = (const int*)d_in[4];
    // d_in[5] is K; fixed at 8 by the problem spec (top-8 structure is compiled in).

    const int S   = in_sizes[3];
    const int HH  = in_sizes[2] / S;
    const int N   = in_sizes[0] / HH;
    const int V   = in_sizes[1] / N;
    const int NBR = in_sizes[4] / (S + V);

    float* Wt   = (float*)d_ws;                                     // S*HH floats
    int*   topk = (int*)((char*)d_ws + (size_t)S * HH * sizeof(float)); // N*8 ints

    float* outg = (float*)d_out;
    float* outS = outg + (size_t)N * V;

    dim3 tb(32, 8);
    dim3 tg((S + 31) / 32, (HH + 31) / 32);
    transposeW<<<tg, tb, 0, stream>>>(W, Wt, S, HH);
    copy_topk<<<N, THREADS, 0, stream>>>(pg, outg, topk, V);
    senses_kernel<<<N, THREADS, 0, stream>>>(hidden, Wt, bias, graph, topk, outS, S, HH, NBR);
}

// Round 3
// 457.655 us; speedup vs baseline: 1.0036x; 1.0036x over previous
//
#include <hip/hip_runtime.h>
#include <float.h>
#include <math.h>

#define THREADS 256

typedef float f32x4 __attribute__((ext_vector_type(4)));   // clang vector: OK for nontemporal builtins

// ---------------------------------------------------------------------------
// Deterministic block reductions (256 threads = 4 waves of 64).
// shfl tree within wave, then fixed-order combine of the 4 wave results.
// All orderings keyed by thread/slot id -> bit-deterministic across replays.
// ---------------------------------------------------------------------------
__device__ __forceinline__ void block_argmax(float& v, int& idx, float* wv, int* wi, int tid) {
    #pragma unroll
    for (int m = 32; m >= 1; m >>= 1) {
        float ov = __shfl_xor(v, m, 64);
        int   oi = __shfl_xor(idx, m, 64);
        if (ov > v || (ov == v && oi < idx)) { v = ov; idx = oi; }
    }
    if ((tid & 63) == 0) { wv[tid >> 6] = v; wi[tid >> 6] = idx; }
    __syncthreads();
    if (tid == 0) {
        float bv = wv[0]; int bi = wi[0];
        #pragma unroll
        for (int w = 1; w < 4; ++w) {
            float cv = wv[w]; int ci = wi[w];
            if (cv > bv || (cv == bv && ci < bi)) { bv = cv; bi = ci; }
        }
        wv[0] = bv; wi[0] = bi;
    }
    __syncthreads();
    v = wv[0]; idx = wi[0];
    __syncthreads();   // protect wv/wi reuse by caller
}

__device__ __forceinline__ float block_sum(float v, float* wv, int tid) {
    #pragma unroll
    for (int m = 32; m >= 1; m >>= 1) v += __shfl_xor(v, m, 64);
    if ((tid & 63) == 0) wv[tid >> 6] = v;
    __syncthreads();
    if (tid == 0) wv[0] = wv[0] + wv[1] + wv[2] + wv[3];
    __syncthreads();
    float r = wv[0];
    __syncthreads();
    return r;
}

// ---------------------------------------------------------------------------
// Kernel A: W[HH][S] -> Wt[S][HH]  (tiled 32x32 transpose)
// ---------------------------------------------------------------------------
__global__ __launch_bounds__(256) void transposeW(const float* __restrict__ W,
                                                  float* __restrict__ Wt,
                                                  int S, int HH) {
    __shared__ float tile[32][33];
    int x  = blockIdx.x * 32 + threadIdx.x;  // s (read)
    int y0 = blockIdx.y * 32;                // h base
    #pragma unroll
    for (int i = threadIdx.y; i < 32; i += 8) {
        int h = y0 + i;
        if (x < S && h < HH) tile[i][threadIdx.x] = W[(size_t)h * S + x];
    }
    __syncthreads();
    #pragma unroll
    for (int i = threadIdx.y; i < 32; i += 8) {
        int s = blockIdx.x * 32 + i;
        int h = y0 + threadIdx.x;
        if (s < S && h < HH) Wt[(size_t)s * HH + h] = tile[threadIdx.x][i];
    }
}

// ---------------------------------------------------------------------------
// Kernel B: per row — copy predictions_globals to out, exact top-8 indices.
// Per-thread sorted top-8 in registers (static indexing only), then 8 rounds
// of deterministic block argmax (tie-break: lowest index = lax.top_k order).
// Streams are nontemporal: data is touched exactly once.
// ---------------------------------------------------------------------------
__global__ __launch_bounds__(THREADS) void copy_topk(const float* __restrict__ pg,
                                                     float* __restrict__ outg,
                                                     int* __restrict__ topk,
                                                     int V) {
    const int row = blockIdx.x, tid = threadIdx.x;
    const f32x4* in4  = (const f32x4*)(pg   + (size_t)row * V);
    f32x4*       out4 = (f32x4*)(outg + (size_t)row * V);
    const int nv = V >> 2;

    float tv[8]; int ti[8];
    #pragma unroll
    for (int p = 0; p < 8; ++p) { tv[p] = -FLT_MAX; ti[p] = 0x7fffffff; }

    for (int i = tid; i < nv; i += THREADS) {
        f32x4 val = __builtin_nontemporal_load(in4 + i);
        __builtin_nontemporal_store(val, out4 + i);
        const int base = i << 2;
        #pragma unroll
        for (int c = 0; c < 4; ++c) {
            float v = val[c];
            if (v > tv[7]) {              // strict >: equal keeps earlier (lower) index
                tv[7] = v; ti[7] = base + c;
                #pragma unroll
                for (int p = 7; p > 0; --p) {
                    if (tv[p] > tv[p - 1]) {
                        float tf = tv[p]; tv[p] = tv[p - 1]; tv[p - 1] = tf;
                        int   tt = ti[p]; ti[p] = ti[p - 1]; ti[p - 1] = tt;
                    }
                }
            }
        }
    }

    __shared__ float wv[4];
    __shared__ int   wi[4];
    for (int r = 0; r < 8; ++r) {
        float v = tv[0]; int idx = ti[0];
        block_argmax(v, idx, wv, wi, tid);
        if (ti[0] == idx) {               // unique owner pops its head
            #pragma unroll
            for (int p = 0; p < 7; ++p) { tv[p] = tv[p + 1]; ti[p] = ti[p + 1]; }
            tv[7] = -FLT_MAX; ti[7] = 0x7fffffff;
        }
        if (tid == 0) topk[row * 8 + r] = idx;
    }
}

// ---------------------------------------------------------------------------
// Kernel C: per row — neighbor gather, dedup, WAVE-COOPERATIVE masked logits,
// softmax, delta subtraction at argmax, write log-probs (log(EPS) off-mask).
//
// Logit phase: one wave computes one sense per iteration. 64 lanes x float4
// = 256 floats = exactly one Wt row -> one fully-coalesced 1KB load, then a
// 6-step shfl_xor reduce. Replaces the per-lane 1KB private stream (64
// scattered 16B requests/instr) that was latency-bound on L3.
// The 492MB log(EPS) fill is issued FIRST (nontemporal, fire-and-forget) so
// its store latency overlaps gather/dedup/dots.
// ---------------------------------------------------------------------------
__global__ __launch_bounds__(THREADS) void senses_kernel(const float* __restrict__ hidden,
                                                         const float* __restrict__ Wt,
                                                         const float* __restrict__ bias,
                                                         const int* __restrict__ graph,
                                                         const int* __restrict__ topk,
                                                         float* __restrict__ outS,
                                                         int S, int NBR) {
    const int row = blockIdx.x, tid = threadIdx.x;
    const int lane = tid & 63, wid = tid >> 6;
    __shared__ float sh_h[THREADS];          // hidden row (HH == 256)
    __shared__ int   cand[THREADS];
    __shared__ float slog[THREADS];          // per-slot logits
    __shared__ int   kk[8];
    __shared__ float wv[4];
    __shared__ int   wi[4];
    __shared__ int   s_cnt;

    // 1) streaming fill of the output row with log(EPS) — issued first,
    //    completes under the compute below (drained by a later barrier).
    const float LOGEPS = -18.420680743952367f;   // logf(1e-8f)
    f32x4* o4 = (f32x4*)(outS + (size_t)row * S);
    f32x4 f4 = { LOGEPS, LOGEPS, LOGEPS, LOGEPS };
    const int nv = S >> 2;
    for (int i = tid; i < nv; i += THREADS) __builtin_nontemporal_store(f4, o4 + i);
    for (int i = (nv << 2) + tid; i < S; i += THREADS)   // tail (S%4, none for 30000)
        outS[(size_t)row * S + i] = LOGEPS;

    // 2) stage hidden row + top-k indices
    sh_h[tid] = hidden[(size_t)row * 256 + tid];
    if (tid < 8) kk[tid] = topk[row * 8 + tid];
    if (tid == 0) s_cnt = 0;
    __syncthreads();

    // 3) gather candidate neighbours: 8 top-K rows x 32 neighbours, coalesced
    const int j = tid >> 5, c = tid & 31;
    const int g = graph[(size_t)(kk[j] + S) * NBR + c] - 1;
    int my = (g >= 0 && g < S) ? g : -1;
    cand[tid] = my;
    __syncthreads();

    // 4) deterministic dedup: owner = lowest slot holding this sense
    //    (iteration t reads cand[t] uniformly -> LDS broadcast, no conflict)
    bool owner = (my >= 0);
    if (owner) {
        for (int t = 0; t < tid; ++t) {
            if (cand[t] == my) { owner = false; break; }
        }
    }
    if (owner) atomicAdd(&s_cnt, 1);        // order-independent count

    // 5) wave-cooperative logits for ALL 256 slots (dups compute redundantly;
    //    invalid slots compute sense 0 — harmless, and exactly what the
    //    zero-neighbour fallback needs at slot 0).
    const f32x4 hreg = ((const f32x4*)sh_h)[lane];   // loop-invariant
    for (int i = 0; i < 64; ++i) {
        const int slot  = (wid << 6) | i;
        const int sense = max(cand[slot], 0);          // wave-uniform broadcast
        const f32x4 w4 = ((const f32x4*)(Wt + (size_t)sense * 256))[lane];
        float p = w4.x * hreg.x + w4.y * hreg.y + w4.z * hreg.z + w4.w * hreg.w;
        #pragma unroll
        for (int m = 32; m >= 1; m >>= 1) p += __shfl_xor(p, m, 64);
        if (lane == 0) slog[slot] = p + bias[sense];
    }
    __syncthreads();   // slog + s_cnt final

    int nsel = s_cnt;
    if (nsel == 0) {                         // zero-neighbour fallback: sense 0
        if (tid == 0) { owner = true; my = 0; }
        nsel = 1;
    }

    const float logit = owner ? slog[tid] : -FLT_MAX;

    // 6) softmax over owners (argmax of p == argmax of logit; tie -> lowest sense)
    float mv = logit;
    int   ai = owner ? my : 0x7fffffff;
    block_argmax(mv, ai, wv, wi, tid);

    const float e = owner ? expf(logit - mv) : 0.f;
    const float sum = block_sum(e, wv, tid);
    // block_sum's barriers have drained the fill stores (vmcnt(0) before
    // s_barrier) -> scatter below safely overwrites filled lanes.

    if (owner) {
        float p = e / sum;
        if (my == ai) p -= 1e-8f * (float)(S - nsel);   // subtract mass at argmax
        outS[(size_t)row * S + my] = logf(p);
    }
}

// ---------------------------------------------------------------------------
extern "C" void kernel_launch(void* const* d_in, const int* in_sizes, int n_in,
                              void* d_out, int out_size, void* d_ws, size_t ws_size,
                              hipStream_t stream) {
    const float* hidden = (const float*)d_in[0];
    const float* pg     = (const float*)d_in[1];
    const float* W      = (const float*)d_in[2];
    const float* bias   = (const float*)d_in[3];
    const int*   graph  = (const int*)d_in[4];
    // d_in[5] is K; fixed at 8 by the problem spec (top-8 structure compiled in).

    const int S   = in_sizes[3];
    const int HH  = in_sizes[2] / S;
    const int N   = in_sizes[0] / HH;
    const int V   = in_sizes[1] / N;
    const int NBR = in_sizes[4] / (S + V);

    float* Wt   = (float*)d_ws;                                        // S*HH floats
    int*   topk = (int*)((char*)d_ws + (size_t)S * HH * sizeof(float)); // N*8 ints

    float* outg = (float*)d_out;
    float* outS = outg + (size_t)N * V;

    dim3 tb(32, 8);
    dim3 tg((S + 31) / 32, (HH + 31) / 32);
    transposeW<<<tg, tb, 0, stream>>>(W, Wt, S, HH);
    copy_topk<<<N, THREADS, 0, stream>>>(pg, outg, topk, V);
    senses_kernel<<<N, THREADS, 0, stream>>>(hidden, Wt, bias, graph, topk, outS, S, NBR);
}

// Round 4
// 454.972 us; speedup vs baseline: 1.0095x; 1.0059x over previous
//
#include <hip/hip_runtime.h>
#include <float.h>
#include <math.h>

#define THREADS 256

typedef float f32x4 __attribute__((ext_vector_type(4)));

// ---------------------------------------------------------------------------
// Deterministic block reductions (256 threads = 4 waves of 64).
// shfl tree within wave, fixed-order combine of the 4 wave results.
// Orderings keyed by thread/slot id -> bit-deterministic across replays.
// ---------------------------------------------------------------------------
__device__ __forceinline__ void block_argmax(float& v, int& idx, float* wv, int* wi, int tid) {
    #pragma unroll
    for (int m = 32; m >= 1; m >>= 1) {
        float ov = __shfl_xor(v, m, 64);
        int   oi = __shfl_xor(idx, m, 64);
        if (ov > v || (ov == v && oi < idx)) { v = ov; idx = oi; }
    }
    if ((tid & 63) == 0) { wv[tid >> 6] = v; wi[tid >> 6] = idx; }
    __syncthreads();
    if (tid == 0) {
        float bv = wv[0]; int bi = wi[0];
        #pragma unroll
        for (int w = 1; w < 4; ++w) {
            float cv = wv[w]; int ci = wi[w];
            if (cv > bv || (cv == bv && ci < bi)) { bv = cv; bi = ci; }
        }
        wv[0] = bv; wi[0] = bi;
    }
    __syncthreads();
    v = wv[0]; idx = wi[0];
    __syncthreads();   // protect wv/wi reuse by caller
}

__device__ __forceinline__ float block_sum(float v, float* wv, int tid) {
    #pragma unroll
    for (int m = 32; m >= 1; m >>= 1) v += __shfl_xor(v, m, 64);
    if ((tid & 63) == 0) wv[tid >> 6] = v;
    __syncthreads();
    if (tid == 0) wv[0] = wv[0] + wv[1] + wv[2] + wv[3];
    __syncthreads();
    float r = wv[0];
    __syncthreads();
    return r;
}

// ---------------------------------------------------------------------------
// Kernel A: W[HH][S] -> Wt[S][HH]  (tiled 32x32 transpose)
// ---------------------------------------------------------------------------
__global__ __launch_bounds__(256) void transposeW(const float* __restrict__ W,
                                                  float* __restrict__ Wt,
                                                  int S, int HH) {
    __shared__ float tile[32][33];
    int x  = blockIdx.x * 32 + threadIdx.x;  // s (read)
    int y0 = blockIdx.y * 32;                // h base
    #pragma unroll
    for (int i = threadIdx.y; i < 32; i += 8) {
        int h = y0 + i;
        if (x < S && h < HH) tile[i][threadIdx.x] = W[(size_t)h * S + x];
    }
    __syncthreads();
    #pragma unroll
    for (int i = threadIdx.y; i < 32; i += 8) {
        int s = blockIdx.x * 32 + i;
        int h = y0 + threadIdx.x;
        if (s < S && h < HH) Wt[(size_t)s * HH + h] = tile[threadIdx.x][i];
    }
}

// ---------------------------------------------------------------------------
// Fused per-row kernel: copy pg -> outg, exact top-8, log(EPS) fill of outS,
// graph gather, dedup, wave-cooperative masked logits, softmax, delta at
// argmax, scatter log-probs.
//
// Fusing all phases into one block means that, block-population-wide, the
// GPU concurrently mixes pg reads + outg writes + outS fill writes + L3 Wt
// reads -> HBM stays saturated instead of running three under-saturated
// serial kernels (R3 post-mortem: 457us vs ~245us traffic floor).
// ---------------------------------------------------------------------------
__global__ __launch_bounds__(THREADS) void fused_row(const float* __restrict__ hidden,
                                                     const float* __restrict__ pg,
                                                     const float* __restrict__ Wt,
                                                     const float* __restrict__ bias,
                                                     const int* __restrict__ graph,
                                                     float* __restrict__ outg,
                                                     float* __restrict__ outS,
                                                     int S, int V, int NBR) {
    const int row = blockIdx.x, tid = threadIdx.x;
    const int lane = tid & 63, wid = tid >> 6;

    __shared__ float sh_h[THREADS];          // hidden row (HH == 256)
    __shared__ int   cand[THREADS];
    __shared__ float slog[THREADS];          // per-slot logits
    __shared__ int   kk[8];
    __shared__ float wv[4];
    __shared__ int   wi[4];
    __shared__ int   s_cnt;

    // stage hidden row + init count early (barrier comes from block_argmax)
    sh_h[tid] = hidden[(size_t)row * 256 + tid];
    if (tid == 0) s_cnt = 0;

    // 1) main streaming loop: copy pg row -> outg row, fill outS row with
    //    log(EPS), per-thread top-8 scan. V == S == 30000 -> one trip count.
    const float LOGEPS = -18.420680743952367f;   // logf(1e-8f)
    const f32x4* in4  = (const f32x4*)(pg   + (size_t)row * V);
    f32x4*       out4 = (f32x4*)(outg + (size_t)row * V);
    f32x4*       o4   = (f32x4*)(outS + (size_t)row * S);
    const f32x4 fill4 = { LOGEPS, LOGEPS, LOGEPS, LOGEPS };
    const int nvV = V >> 2, nvS = S >> 2;
    const int nvMin = (nvV < nvS) ? nvV : nvS;

    float tv[8]; int ti[8];
    #pragma unroll
    for (int p = 0; p < 8; ++p) { tv[p] = -FLT_MAX; ti[p] = 0x7fffffff; }

    for (int i = tid; i < nvMin; i += THREADS) {
        f32x4 val = __builtin_nontemporal_load(in4 + i);
        __builtin_nontemporal_store(val,   out4 + i);
        __builtin_nontemporal_store(fill4, o4   + i);
        const int base = i << 2;
        #pragma unroll
        for (int c = 0; c < 4; ++c) {
            float v = val[c];
            if (v > tv[7]) {              // strict >: equal keeps earlier (lower) index
                tv[7] = v; ti[7] = base + c;
                #pragma unroll
                for (int p = 7; p > 0; --p) {
                    if (tv[p] > tv[p - 1]) {
                        float tf = tv[p]; tv[p] = tv[p - 1]; tv[p - 1] = tf;
                        int   tt = ti[p]; ti[p] = ti[p - 1]; ti[p - 1] = tt;
                    }
                }
            }
        }
    }
    // tails (none for V == S == 30000, kept for generality)
    for (int i = nvMin; i < nvV; i += 0) break;  // unreachable when V==S
    for (int i = (nvV << 2) + tid; i < V; i += THREADS) {
        float v = pg[(size_t)row * V + i];
        outg[(size_t)row * V + i] = v;
        if (v > tv[7]) {
            tv[7] = v; ti[7] = i;
            #pragma unroll
            for (int p = 7; p > 0; --p) {
                if (tv[p] > tv[p - 1]) {
                    float tf = tv[p]; tv[p] = tv[p - 1]; tv[p - 1] = tf;
                    int   tt = ti[p]; ti[p] = ti[p - 1]; ti[p - 1] = tt;
                }
            }
        }
    }
    for (int i = (nvS << 2) + tid; i < S; i += THREADS)
        outS[(size_t)row * S + i] = LOGEPS;

    // 2) exact block top-8 (tie-break lowest index = lax.top_k order)
    for (int r = 0; r < 8; ++r) {
        float v = tv[0]; int idx = ti[0];
        block_argmax(v, idx, wv, wi, tid);
        if (ti[0] == idx) {               // unique owner pops its head
            #pragma unroll
            for (int p = 0; p < 7; ++p) { tv[p] = tv[p + 1]; ti[p] = ti[p + 1]; }
            tv[7] = -FLT_MAX; ti[7] = 0x7fffffff;
        }
        if (tid == 0) kk[r] = idx;
    }
    __syncthreads();

    // 3) gather candidate neighbours: 8 top-K rows x 32 neighbours, coalesced
    const int j = tid >> 5, c = tid & 31;
    const int g = graph[(size_t)(kk[j] + S) * NBR + c] - 1;
    int my = (g >= 0 && g < S) ? g : -1;
    cand[tid] = my;
    __syncthreads();

    // 4) deterministic dedup: owner = lowest slot holding this sense
    bool owner = (my >= 0);
    if (owner) {
        for (int t = 0; t < tid; ++t) {
            if (cand[t] == my) { owner = false; break; }
        }
    }
    if (owner) atomicAdd(&s_cnt, 1);        // order-independent count

    // 5) wave-cooperative logits for all 256 slots (dups/invalid redundant;
    //    invalid -> sense 0, which is exactly the zero-neighbour fallback).
    const f32x4 hreg = ((const f32x4*)sh_h)[lane];
    for (int i = 0; i < 64; ++i) {
        const int slot  = (wid << 6) | i;
        const int sense = max(cand[slot], 0);          // wave-uniform broadcast
        const f32x4 w4 = ((const f32x4*)(Wt + (size_t)sense * 256))[lane];
        float p = w4.x * hreg.x + w4.y * hreg.y + w4.z * hreg.z + w4.w * hreg.w;
        #pragma unroll
        for (int m = 32; m >= 1; m >>= 1) p += __shfl_xor(p, m, 64);
        if (lane == 0) slog[slot] = p + bias[sense];
    }
    __syncthreads();   // slog + s_cnt final

    int nsel = s_cnt;
    if (nsel == 0) {                         // zero-neighbour fallback: sense 0
        if (tid == 0) { owner = true; my = 0; }
        nsel = 1;
    }

    const float logit = owner ? slog[tid] : -FLT_MAX;

    // 6) softmax over owners (argmax of p == argmax of logit; tie -> lowest)
    float mv = logit;
    int   ai = owner ? my : 0x7fffffff;
    block_argmax(mv, ai, wv, wi, tid);

    const float e = owner ? expf(logit - mv) : 0.f;
    const float sum = block_sum(e, wv, tid);
    // block_sum's barriers drain the fill stores (vmcnt(0) before s_barrier)
    // -> the scatter below safely overwrites filled lanes of this row.

    if (owner) {
        float p = e / sum;
        if (my == ai) p -= 1e-8f * (float)(S - nsel);   // subtract mass at argmax
        outS[(size_t)row * S + my] = logf(p);
    }
}

// ---------------------------------------------------------------------------
extern "C" void kernel_launch(void* const* d_in, const int* in_sizes, int n_in,
                              void* d_out, int out_size, void* d_ws, size_t ws_size,
                              hipStream_t stream) {
    const float* hidden = (const float*)d_in[0];
    const float* pg     = (const float*)d_in[1];
    const float* W      = (const float*)d_in[2];
    const float* bias   = (const float*)d_in[3];
    const int*   graph  = (const int*)d_in[4];
    // d_in[5] is K; fixed at 8 by the problem spec (top-8 structure compiled in).

    const int S   = in_sizes[3];
    const int HH  = in_sizes[2] / S;
    const int N   = in_sizes[0] / HH;
    const int V   = in_sizes[1] / N;
    const int NBR = in_sizes[4] / (S + V);

    float* Wt = (float*)d_ws;                 // S*HH floats

    float* outg = (float*)d_out;
    float* outS = outg + (size_t)N * V;

    dim3 tb(32, 8);
    dim3 tg((S + 31) / 32, (HH + 31) / 32);
    transposeW<<<tg, tb, 0, stream>>>(W, Wt, S, HH);
    fused_row<<<N, THREADS, 0, stream>>>(hidden, pg, Wt, bias, graph,
                                         outg, outS, S, V, NBR);
}